// Round 9
// baseline (240.105 us; speedup 1.0000x reference)
//
#include <hip/hip_runtime.h>
#include <math.h>

#define LEN_Q 13294
#define NFRAMES 2
#define MTOT (LEN_Q * NFRAMES)   // 26588
#define HEADS 8
#define LEVELS 4
#define POINTS 4

typedef __attribute__((ext_vector_type(8))) short short8;
typedef __attribute__((ext_vector_type(4))) float f32x4;
typedef __attribute__((ext_vector_type(2))) float f32x2;
typedef __attribute__((ext_vector_type(2))) unsigned int uint2v;
typedef __attribute__((ext_vector_type(4))) unsigned int uint4v;
typedef __attribute__((ext_vector_type(4))) unsigned short ushort4v;

__device__ __forceinline__ unsigned short f2bf(float x) {
    unsigned u = __builtin_bit_cast(unsigned, x);
    unsigned r = (u + 0x7fffu + ((u >> 16) & 1u)) >> 16;
    return (unsigned short)r;
}
__device__ __forceinline__ float bf2f(unsigned short b) {
    return __builtin_bit_cast(float, (unsigned)b << 16);
}

#define LSTR 40   // LDS row stride (shorts)

// ---------------------------------------------------------------------------
// prep: all 4 weight transposes f32[K,N] -> bf16[N,K] in one dispatch.
// ---------------------------------------------------------------------------
__global__ __launch_bounds__(256) void prep_weights(
    const float* __restrict__ Wv,  const float* __restrict__ Woff,
    const float* __restrict__ Wat, const float* __restrict__ Wout,
    unsigned short* __restrict__ wvT,   // 256x256
    unsigned short* __restrict__ woaT,  // 384x256
    unsigned short* __restrict__ woutT) // 256x256
{
    const int b = blockIdx.x;
    const int k = threadIdx.x;
    const float* src; unsigned short* dst; int N; int n;
    if (b < 256)      { src = Wv;   dst = wvT;          N = 256; n = b; }
    else if (b < 512) { src = Woff; dst = woaT;         N = 256; n = b - 256; }
    else if (b < 640) { src = Wat;  dst = woaT + 65536; N = 128; n = b - 512; }
    else              { src = Wout; dst = woutT;        N = 256; n = b - 640; }
    dst[(size_t)n * 256 + k] = f2bf(src[(size_t)k * N + n]);
}

// ---------------------------------------------------------------------------
// Fused GEMM (R5/R8 structure + register prefetch pipeline).
// n-tiles 0,1 -> value = inflat@Wv+bv ; n-tiles 2,3,4 -> off|attn.
// Prefetch: iter k+1's global loads issue before iter k's MFMAs, so the
// vmcnt drain at the next barrier overlaps a full MFMA phase.
// ---------------------------------------------------------------------------
__global__ __launch_bounds__(256, 3) void gemm_fused(
    const float* __restrict__ Aval,
    const float* __restrict__ Aq,
    const unsigned short* __restrict__ BTv,   // [256,256]
    const unsigned short* __restrict__ BToa,  // [384,256]
    const float* __restrict__ bv,
    const float* __restrict__ boff,
    const float* __restrict__ battn,
    unsigned short* __restrict__ v16,
    unsigned short* __restrict__ off16,
    unsigned short* __restrict__ at16,
    int M, int K)
{
    __shared__ unsigned short As[128 * LSTR];
    __shared__ unsigned short Bs[128 * LSTR];

    const int t = threadIdx.x;
    const int w = t >> 6;
    const int L = t & 63;
    const int m0 = blockIdx.y * 128;
    const bool isVal = (blockIdx.x < 2);
    const int nTile = isVal ? blockIdx.x : blockIdx.x - 2;
    const float* Af = isVal ? Aval : Aq;
    const unsigned short* BTb = (isVal ? BTv : BToa) + (size_t)nTile * 128 * K;

    const int sr = t >> 1;
    const int sc = (t & 1) * 16;
    int arow = m0 + sr; if (arow > M - 1) arow = M - 1;
    const float* Ag = Af + (size_t)arow * K + sc;
    const unsigned short* Bg = BTb + (size_t)sr * K + sc;
    unsigned short* AsW = &As[sr * LSTR + sc];
    unsigned short* BsW = &Bs[sr * LSTR + sc];

    const int mq = (w & 1) * 64;
    const int nq = (w >> 1) * 64;
    const int lr = L & 15;
    const int kq = (L >> 4) * 8;

    f32x4 acc[4][4];
    #pragma unroll
    for (int i = 0; i < 4; ++i)
        #pragma unroll
        for (int j = 0; j < 4; ++j) acc[i][j] = (f32x4){0.f, 0.f, 0.f, 0.f};

    // prologue: load k0 = 0
    f32x4 a0 = *(const f32x4*)(Ag);
    f32x4 a1 = *(const f32x4*)(Ag + 4);
    f32x4 a2 = *(const f32x4*)(Ag + 8);
    f32x4 a3 = *(const f32x4*)(Ag + 12);
    short8 b0 = *(const short8*)(Bg);
    short8 b1 = *(const short8*)(Bg + 8);

    for (int k0 = 0; k0 < K; k0 += 32) {
        short8 p0, p1;
        p0[0]=(short)f2bf(a0.x); p0[1]=(short)f2bf(a0.y); p0[2]=(short)f2bf(a0.z); p0[3]=(short)f2bf(a0.w);
        p0[4]=(short)f2bf(a1.x); p0[5]=(short)f2bf(a1.y); p0[6]=(short)f2bf(a1.z); p0[7]=(short)f2bf(a1.w);
        p1[0]=(short)f2bf(a2.x); p1[1]=(short)f2bf(a2.y); p1[2]=(short)f2bf(a2.z); p1[3]=(short)f2bf(a2.w);
        p1[4]=(short)f2bf(a3.x); p1[5]=(short)f2bf(a3.y); p1[6]=(short)f2bf(a3.z); p1[7]=(short)f2bf(a3.w);
        __syncthreads();
        *(short8*)(AsW) = p0;
        *(short8*)(AsW + 8) = p1;
        *(short8*)(BsW) = b0;
        *(short8*)(BsW + 8) = b1;
        __syncthreads();

        if (k0 + 32 < K) {              // prefetch next tile (reg-private)
            a0 = *(const f32x4*)(Ag + k0 + 32);
            a1 = *(const f32x4*)(Ag + k0 + 36);
            a2 = *(const f32x4*)(Ag + k0 + 40);
            a3 = *(const f32x4*)(Ag + k0 + 44);
            b0 = *(const short8*)(Bg + k0 + 32);
            b1 = *(const short8*)(Bg + k0 + 40);
        }

        short8 af[4], bf[4];
        #pragma unroll
        for (int i = 0; i < 4; ++i)
            af[i] = *(const short8*)&As[(mq + i * 16 + lr) * LSTR + kq];
        #pragma unroll
        for (int j = 0; j < 4; ++j)
            bf[j] = *(const short8*)&Bs[(nq + j * 16 + lr) * LSTR + kq];
        #pragma unroll
        for (int i = 0; i < 4; ++i)
            #pragma unroll
            for (int j = 0; j < 4; ++j)
                acc[i][j] = __builtin_amdgcn_mfma_f32_16x16x32_bf16(af[i], bf[j], acc[i][j], 0, 0, 0);
    }

    const int rr = (L >> 4) * 4;
    #pragma unroll
    for (int i = 0; i < 4; ++i) {
        #pragma unroll
        for (int r = 0; r < 4; ++r) {
            int m = m0 + mq + i * 16 + rr + r;
            if (m < M) {
                #pragma unroll
                for (int j = 0; j < 4; ++j) {
                    int colg = nTile * 128 + nq + j * 16 + lr;
                    float v = acc[i][j][r];
                    if (isVal) {
                        v16[(size_t)m * 256 + colg] = f2bf(v + bv[colg]);
                    } else if (colg < 256) {
                        off16[(size_t)m * 256 + colg] = f2bf(v + boff[colg]);
                    } else {
                        at16[(size_t)m * 128 + (colg - 256)] = f2bf(v + battn[colg - 256]);
                    }
                }
            }
        }
    }
}

// ---------------------------------------------------------------------------
// Output GEMM (R8 structure + register prefetch pipeline).
// ---------------------------------------------------------------------------
__global__ __launch_bounds__(256, 3) void gemm_out(
    const unsigned short* __restrict__ A,
    const unsigned short* __restrict__ BT,
    const float* __restrict__ bias,
    float* __restrict__ C,
    int M, int K)
{
    __shared__ unsigned short As[128 * LSTR];
    __shared__ unsigned short Bs[128 * LSTR];

    const int t = threadIdx.x;
    const int w = t >> 6;
    const int L = t & 63;
    const int m0 = blockIdx.y * 128;
    const int n0 = blockIdx.x * 128;

    const int sr = t >> 1;
    const int sc = (t & 1) * 16;
    int arow = m0 + sr; if (arow > M - 1) arow = M - 1;
    const unsigned short* Ag = A + (size_t)arow * K + sc;
    const unsigned short* Bg = BT + (size_t)(n0 + sr) * K + sc;
    unsigned short* AsW = &As[sr * LSTR + sc];
    unsigned short* BsW = &Bs[sr * LSTR + sc];

    const int mq = (w & 1) * 64;
    const int nq = (w >> 1) * 64;
    const int lr = L & 15;
    const int kq = (L >> 4) * 8;

    f32x4 acc[4][4];
    #pragma unroll
    for (int i = 0; i < 4; ++i)
        #pragma unroll
        for (int j = 0; j < 4; ++j) acc[i][j] = (f32x4){0.f, 0.f, 0.f, 0.f};

    short8 a0 = *(const short8*)(Ag);
    short8 a1 = *(const short8*)(Ag + 8);
    short8 b0 = *(const short8*)(Bg);
    short8 b1 = *(const short8*)(Bg + 8);

    for (int k0 = 0; k0 < K; k0 += 32) {
        __syncthreads();
        *(short8*)(AsW) = a0;
        *(short8*)(AsW + 8) = a1;
        *(short8*)(BsW) = b0;
        *(short8*)(BsW + 8) = b1;
        __syncthreads();

        if (k0 + 32 < K) {
            a0 = *(const short8*)(Ag + k0 + 32);
            a1 = *(const short8*)(Ag + k0 + 40);
            b0 = *(const short8*)(Bg + k0 + 32);
            b1 = *(const short8*)(Bg + k0 + 40);
        }

        short8 af[4], bf[4];
        #pragma unroll
        for (int i = 0; i < 4; ++i)
            af[i] = *(const short8*)&As[(mq + i * 16 + lr) * LSTR + kq];
        #pragma unroll
        for (int j = 0; j < 4; ++j)
            bf[j] = *(const short8*)&Bs[(nq + j * 16 + lr) * LSTR + kq];
        #pragma unroll
        for (int i = 0; i < 4; ++i)
            #pragma unroll
            for (int j = 0; j < 4; ++j)
                acc[i][j] = __builtin_amdgcn_mfma_f32_16x16x32_bf16(af[i], bf[j], acc[i][j], 0, 0, 0);
    }

    const int rr = (L >> 4) * 4;
    #pragma unroll
    for (int i = 0; i < 4; ++i) {
        #pragma unroll
        for (int r = 0; r < 4; ++r) {
            int m = m0 + mq + i * 16 + rr + r;
            if (m < M) {
                #pragma unroll
                for (int j = 0; j < 4; ++j) {
                    int n = n0 + nq + j * 16 + lr;
                    C[(size_t)m * 256 + n] = acc[i][j][r] + bias[n];
                }
            }
        }
    }
}

// ---------------------------------------------------------------------------
// Sampler v6: NO per-sample LDS reads. Each lane serves head h = L>>3 and
// computes that head's (wt, idx) in-register inside the gather loop
// (formulas bit-identical to R8's phase 3, redundant across the 8 lanes of
// a head). Off-channels for the head preloaded as one 64-B broadcast load;
// refpts/spatial/lsi preloaded. Softmax stays in LDS (16 reads/wave, was
// 128 w_s/idx_s reads). LDS 2 KB. XCD-swizzled grid.
// ---------------------------------------------------------------------------
__global__ __launch_bounds__(256) void sample6(
    const unsigned short* __restrict__ value,  // bf16 [MTOT,256]
    const unsigned short* __restrict__ off,    // bf16 [MTOT,256]
    const unsigned short* __restrict__ attn,   // bf16 [MTOT,128]
    const float* __restrict__ refpts,          // [LEN_Q, LEVELS, 2]
    const int*   __restrict__ spatial,         // [LEVELS,2] (H,W)
    const int*   __restrict__ lsi,             // [LEVELS]
    unsigned short* __restrict__ samp)         // bf16 [MTOT,256]
{
    const int b = blockIdx.x;
    const int newb = (b & 7) * 831 + (b >> 3);
    if (newb * 4 >= MTOT) return;
    const int w = threadIdx.x >> 6;
    const int L = threadIdx.x & 63;
    const int row = newb * 4 + w;
    const int frame = row >= LEN_Q ? 1 : 0;
    const int q = row - frame * LEN_Q;
    const int h = L >> 3;

    __shared__ float attn_s[4][HEADS][16];

    // ---- phase 1: attn -> LDS ----
    {
        unsigned av = *(const unsigned*)(attn + (size_t)row * 128 + 2 * L);
        int t0 = 2 * L;
        attn_s[w][t0 >> 4][t0 & 15] = bf2f((unsigned short)(av & 0xffffu));
        attn_s[w][(t0 + 1) >> 4][(t0 + 1) & 15] = bf2f((unsigned short)(av >> 16));
    }

    // ---- preloads (no sync needed yet; register-private) ----
    unsigned od[16];                       // this head's 32 off-channels (bf16)
    {
        const unsigned short* orow = off + (size_t)row * 256 + h * 32;
        *(uint4v*)&od[0]  = *(const uint4v*)(orow);
        *(uint4v*)&od[4]  = *(const uint4v*)(orow + 8);
        *(uint4v*)&od[8]  = *(const uint4v*)(orow + 16);
        *(uint4v*)&od[12] = *(const uint4v*)(orow + 24);
    }
    float rx[4], ry[4];
    int   Hl[4], Wl[4], st[4];
    #pragma unroll
    for (int l = 0; l < 4; ++l) {
        f32x2 rv = *(const f32x2*)(refpts + ((size_t)q * LEVELS + l) * 2);
        rx[l] = rv.x; ry[l] = rv.y;
        Hl[l] = spatial[l * 2];
        Wl[l] = spatial[l * 2 + 1];
        st[l] = lsi[l];
    }
    __syncthreads();

    // ---- phase 2: softmax per head ----
    if (L < 8) {
        float m = attn_s[w][L][0];
        #pragma unroll
        for (int i = 1; i < 16; ++i) m = fmaxf(m, attn_s[w][L][i]);
        float e[16]; float s = 0.f;
        #pragma unroll
        for (int i = 0; i < 16; ++i) { e[i] = __expf(attn_s[w][L][i] - m); s += e[i]; }
        float inv = 1.f / s;
        #pragma unroll
        for (int i = 0; i < 16; ++i) attn_s[w][L][i] = e[i] * inv;
    }
    __syncthreads();

    // ---- gather: per-lp in-register (wt,idx) + 4 corner gathers ----
    const char* vbase = (const char*)value + (size_t)frame * LEN_Q * 512 + 8 * L;
    float a0 = 0.f, a1 = 0.f, a2 = 0.f, a3 = 0.f;
    #pragma unroll
    for (int lp = 0; lp < 16; ++lp) {
        const int l = lp >> 2;
        float wt = attn_s[w][h][lp];
        float ox = bf2f((unsigned short)(od[lp] & 0xffffu));
        float oy = bf2f((unsigned short)(od[lp] >> 16));
        float locx = rx[l] + ox * __builtin_amdgcn_rcpf((float)Wl[l]);
        float locy = ry[l] + oy * __builtin_amdgcn_rcpf((float)Hl[l]);
        float x = locx * (float)Wl[l] - 0.5f;
        float y = locy * (float)Hl[l] - 0.5f;
        float x0f = floorf(x), y0f = floorf(y);
        float lx = x - x0f, ly = y - y0f;
        int x0 = (int)x0f, y0 = (int)y0f;
        int x1 = x0 + 1, y1 = y0 + 1;
        int vx0 = (x0 >= 0) & (x0 < Wl[l]);
        int vx1 = (x1 >= 0) & (x1 < Wl[l]);
        int vy0 = (y0 >= 0) & (y0 < Hl[l]);
        int vy1 = (y1 >= 0) & (y1 < Hl[l]);
        int x0c = min(max(x0, 0), Wl[l] - 1);
        int x1c = min(max(x1, 0), Wl[l] - 1);
        int y0c = min(max(y0, 0), Hl[l] - 1);
        int y1c = min(max(y1, 0), Hl[l] - 1);
        int i00 = (st[l] + y0c * Wl[l] + x0c) * 512;
        int i01 = (st[l] + y0c * Wl[l] + x1c) * 512;
        int i10 = (st[l] + y1c * Wl[l] + x0c) * 512;
        int i11 = (st[l] + y1c * Wl[l] + x1c) * 512;
        float w00 = (vy0 & vx0) ? wt * (1.f - lx) * (1.f - ly) : 0.f;
        float w01 = (vy0 & vx1) ? wt * lx * (1.f - ly) : 0.f;
        float w10 = (vy1 & vx0) ? wt * (1.f - lx) * ly : 0.f;
        float w11 = (vy1 & vx1) ? wt * lx * ly : 0.f;
        const float wts[4] = {w00, w01, w10, w11};
        const int   idc[4] = {i00, i01, i10, i11};
        #pragma unroll
        for (int cr = 0; cr < 4; ++cr) {
            uint2v v = *(const uint2v*)(vbase + (size_t)idc[cr]);
            float wc = wts[cr];
            a0 = fmaf(wc, __builtin_bit_cast(float, v.x << 16), a0);
            a1 = fmaf(wc, __builtin_bit_cast(float, v.x & 0xffff0000u), a1);
            a2 = fmaf(wc, __builtin_bit_cast(float, v.y << 16), a2);
            a3 = fmaf(wc, __builtin_bit_cast(float, v.y & 0xffff0000u), a3);
        }
    }
    ushort4v o;
    o.x = f2bf(a0); o.y = f2bf(a1); o.z = f2bf(a2); o.w = f2bf(a3);
    *(ushort4v*)(samp + (size_t)row * 256 + 4 * L) = o;
}

// ---------------------------------------------------------------------------
extern "C" void kernel_launch(void* const* d_in, const int* in_sizes, int n_in,
                              void* d_out, int out_size, void* d_ws, size_t ws_size,
                              hipStream_t stream)
{
    const float* query   = (const float*)d_in[0];
    const float* refpts  = (const float*)d_in[1];
    const float* inflat  = (const float*)d_in[2];
    const int*   spatial = (const int*)d_in[3];
    const int*   lsi     = (const int*)d_in[4];
    const float* Wv      = (const float*)d_in[5];
    const float* bv      = (const float*)d_in[6];
    const float* Woff    = (const float*)d_in[7];
    const float* boff    = (const float*)d_in[8];
    const float* Wattn   = (const float*)d_in[9];
    const float* battn   = (const float*)d_in[10];
    const float* Wout    = (const float*)d_in[11];
    const float* bout    = (const float*)d_in[12];

    unsigned short* ws = (unsigned short*)d_ws;
    const size_t MR = (size_t)MTOT * 256;
    unsigned short* v16    = ws;                        // MTOT*256
    unsigned short* off16  = v16 + MR;                  // MTOT*256
    unsigned short* at16   = off16 + MR;                // MTOT*128
    unsigned short* samp16 = at16 + (size_t)MTOT * 128; // MTOT*256
    unsigned short* wvT    = samp16 + MR;               // 256*256
    unsigned short* woaT   = wvT + 65536;               // 384*256
    unsigned short* woutT  = woaT + 98304;              // 256*256

    dim3 blk256(256);
    const int mBlocks = (MTOT + 127) / 128;             // 208

    hipLaunchKernelGGL(prep_weights, dim3(896), blk256, 0, stream,
                       Wv, Woff, Wattn, Wout, wvT, woaT, woutT);

    hipLaunchKernelGGL(gemm_fused, dim3(5, mBlocks), blk256, 0, stream,
                       inflat, query, wvT, woaT, bv, boff, battn,
                       v16, off16, at16, MTOT, 256);

    hipLaunchKernelGGL(sample6, dim3(6648), blk256, 0, stream,
                       v16, off16, at16, refpts, spatial, lsi, samp16);

    hipLaunchKernelGGL(gemm_out, dim3(2, mBlocks), blk256, 0, stream,
                       samp16, woutT, bout, (float*)d_out, MTOT, 256);
}

// Round 10
// 228.570 us; speedup vs baseline: 1.0505x; 1.0505x over previous
//
#include <hip/hip_runtime.h>
#include <math.h>

#define LEN_Q 13294
#define NFRAMES 2
#define MTOT (LEN_Q * NFRAMES)   // 26588
#define HEADS 8
#define LEVELS 4
#define POINTS 4

typedef __attribute__((ext_vector_type(8))) short short8;
typedef __attribute__((ext_vector_type(4))) float f32x4;
typedef __attribute__((ext_vector_type(2))) unsigned int uint2v;
typedef __attribute__((ext_vector_type(4))) unsigned short ushort4v;

__device__ __forceinline__ unsigned short f2bf(float x) {
    unsigned u = __builtin_bit_cast(unsigned, x);
    unsigned r = (u + 0x7fffu + ((u >> 16) & 1u)) >> 16;
    return (unsigned short)r;
}
__device__ __forceinline__ float bf2f(unsigned short b) {
    return __builtin_bit_cast(float, (unsigned)b << 16);
}

#define LSTR 40   // LDS row stride (shorts)

// ---------------------------------------------------------------------------
// prep: all 4 weight transposes f32[K,N] -> bf16[N,K] in one dispatch.
// ---------------------------------------------------------------------------
__global__ __launch_bounds__(256) void prep_weights(
    const float* __restrict__ Wv,  const float* __restrict__ Woff,
    const float* __restrict__ Wat, const float* __restrict__ Wout,
    unsigned short* __restrict__ wvT,   // 256x256
    unsigned short* __restrict__ woaT,  // 384x256
    unsigned short* __restrict__ woutT) // 256x256
{
    const int b = blockIdx.x;
    const int k = threadIdx.x;
    const float* src; unsigned short* dst; int N; int n;
    if (b < 256)      { src = Wv;   dst = wvT;          N = 256; n = b; }
    else if (b < 512) { src = Woff; dst = woaT;         N = 256; n = b - 256; }
    else if (b < 640) { src = Wat;  dst = woaT + 65536; N = 128; n = b - 512; }
    else              { src = Wout; dst = woutT;        N = 256; n = b - 640; }
    dst[(size_t)n * 256 + k] = f2bf(src[(size_t)k * N + n]);
}

// ---------------------------------------------------------------------------
// Fused GEMM (R9: R5 structure + register prefetch pipeline — kept, it won).
// ---------------------------------------------------------------------------
__global__ __launch_bounds__(256, 3) void gemm_fused(
    const float* __restrict__ Aval,
    const float* __restrict__ Aq,
    const unsigned short* __restrict__ BTv,   // [256,256]
    const unsigned short* __restrict__ BToa,  // [384,256]
    const float* __restrict__ bv,
    const float* __restrict__ boff,
    const float* __restrict__ battn,
    unsigned short* __restrict__ v16,
    unsigned short* __restrict__ off16,
    unsigned short* __restrict__ at16,
    int M, int K)
{
    __shared__ unsigned short As[128 * LSTR];
    __shared__ unsigned short Bs[128 * LSTR];

    const int t = threadIdx.x;
    const int w = t >> 6;
    const int L = t & 63;
    const int m0 = blockIdx.y * 128;
    const bool isVal = (blockIdx.x < 2);
    const int nTile = isVal ? blockIdx.x : blockIdx.x - 2;
    const float* Af = isVal ? Aval : Aq;
    const unsigned short* BTb = (isVal ? BTv : BToa) + (size_t)nTile * 128 * K;

    const int sr = t >> 1;
    const int sc = (t & 1) * 16;
    int arow = m0 + sr; if (arow > M - 1) arow = M - 1;
    const float* Ag = Af + (size_t)arow * K + sc;
    const unsigned short* Bg = BTb + (size_t)sr * K + sc;
    unsigned short* AsW = &As[sr * LSTR + sc];
    unsigned short* BsW = &Bs[sr * LSTR + sc];

    const int mq = (w & 1) * 64;
    const int nq = (w >> 1) * 64;
    const int lr = L & 15;
    const int kq = (L >> 4) * 8;

    f32x4 acc[4][4];
    #pragma unroll
    for (int i = 0; i < 4; ++i)
        #pragma unroll
        for (int j = 0; j < 4; ++j) acc[i][j] = (f32x4){0.f, 0.f, 0.f, 0.f};

    f32x4 a0 = *(const f32x4*)(Ag);
    f32x4 a1 = *(const f32x4*)(Ag + 4);
    f32x4 a2 = *(const f32x4*)(Ag + 8);
    f32x4 a3 = *(const f32x4*)(Ag + 12);
    short8 b0 = *(const short8*)(Bg);
    short8 b1 = *(const short8*)(Bg + 8);

    for (int k0 = 0; k0 < K; k0 += 32) {
        short8 p0, p1;
        p0[0]=(short)f2bf(a0.x); p0[1]=(short)f2bf(a0.y); p0[2]=(short)f2bf(a0.z); p0[3]=(short)f2bf(a0.w);
        p0[4]=(short)f2bf(a1.x); p0[5]=(short)f2bf(a1.y); p0[6]=(short)f2bf(a1.z); p0[7]=(short)f2bf(a1.w);
        p1[0]=(short)f2bf(a2.x); p1[1]=(short)f2bf(a2.y); p1[2]=(short)f2bf(a2.z); p1[3]=(short)f2bf(a2.w);
        p1[4]=(short)f2bf(a3.x); p1[5]=(short)f2bf(a3.y); p1[6]=(short)f2bf(a3.z); p1[7]=(short)f2bf(a3.w);
        __syncthreads();
        *(short8*)(AsW) = p0;
        *(short8*)(AsW + 8) = p1;
        *(short8*)(BsW) = b0;
        *(short8*)(BsW + 8) = b1;
        __syncthreads();

        if (k0 + 32 < K) {              // prefetch next tile (reg-private)
            a0 = *(const f32x4*)(Ag + k0 + 32);
            a1 = *(const f32x4*)(Ag + k0 + 36);
            a2 = *(const f32x4*)(Ag + k0 + 40);
            a3 = *(const f32x4*)(Ag + k0 + 44);
            b0 = *(const short8*)(Bg + k0 + 32);
            b1 = *(const short8*)(Bg + k0 + 40);
        }

        short8 af[4], bf[4];
        #pragma unroll
        for (int i = 0; i < 4; ++i)
            af[i] = *(const short8*)&As[(mq + i * 16 + lr) * LSTR + kq];
        #pragma unroll
        for (int j = 0; j < 4; ++j)
            bf[j] = *(const short8*)&Bs[(nq + j * 16 + lr) * LSTR + kq];
        #pragma unroll
        for (int i = 0; i < 4; ++i)
            #pragma unroll
            for (int j = 0; j < 4; ++j)
                acc[i][j] = __builtin_amdgcn_mfma_f32_16x16x32_bf16(af[i], bf[j], acc[i][j], 0, 0, 0);
    }

    const int rr = (L >> 4) * 4;
    #pragma unroll
    for (int i = 0; i < 4; ++i) {
        #pragma unroll
        for (int r = 0; r < 4; ++r) {
            int m = m0 + mq + i * 16 + rr + r;
            if (m < M) {
                #pragma unroll
                for (int j = 0; j < 4; ++j) {
                    int colg = nTile * 128 + nq + j * 16 + lr;
                    float v = acc[i][j][r];
                    if (isVal) {
                        v16[(size_t)m * 256 + colg] = f2bf(v + bv[colg]);
                    } else if (colg < 256) {
                        off16[(size_t)m * 256 + colg] = f2bf(v + boff[colg]);
                    } else {
                        at16[(size_t)m * 128 + (colg - 256)] = f2bf(v + battn[colg - 256]);
                    }
                }
            }
        }
    }
}

// ---------------------------------------------------------------------------
// Output GEMM (R9 register-prefetch version — kept).
// ---------------------------------------------------------------------------
__global__ __launch_bounds__(256, 3) void gemm_out(
    const unsigned short* __restrict__ A,
    const unsigned short* __restrict__ BT,
    const float* __restrict__ bias,
    float* __restrict__ C,
    int M, int K)
{
    __shared__ unsigned short As[128 * LSTR];
    __shared__ unsigned short Bs[128 * LSTR];

    const int t = threadIdx.x;
    const int w = t >> 6;
    const int L = t & 63;
    const int m0 = blockIdx.y * 128;
    const int n0 = blockIdx.x * 128;

    const int sr = t >> 1;
    const int sc = (t & 1) * 16;
    int arow = m0 + sr; if (arow > M - 1) arow = M - 1;
    const unsigned short* Ag = A + (size_t)arow * K + sc;
    const unsigned short* Bg = BT + (size_t)(n0 + sr) * K + sc;
    unsigned short* AsW = &As[sr * LSTR + sc];
    unsigned short* BsW = &Bs[sr * LSTR + sc];

    const int mq = (w & 1) * 64;
    const int nq = (w >> 1) * 64;
    const int lr = L & 15;
    const int kq = (L >> 4) * 8;

    f32x4 acc[4][4];
    #pragma unroll
    for (int i = 0; i < 4; ++i)
        #pragma unroll
        for (int j = 0; j < 4; ++j) acc[i][j] = (f32x4){0.f, 0.f, 0.f, 0.f};

    short8 a0 = *(const short8*)(Ag);
    short8 a1 = *(const short8*)(Ag + 8);
    short8 b0 = *(const short8*)(Bg);
    short8 b1 = *(const short8*)(Bg + 8);

    for (int k0 = 0; k0 < K; k0 += 32) {
        __syncthreads();
        *(short8*)(AsW) = a0;
        *(short8*)(AsW + 8) = a1;
        *(short8*)(BsW) = b0;
        *(short8*)(BsW + 8) = b1;
        __syncthreads();

        if (k0 + 32 < K) {
            a0 = *(const short8*)(Ag + k0 + 32);
            a1 = *(const short8*)(Ag + k0 + 40);
            b0 = *(const short8*)(Bg + k0 + 32);
            b1 = *(const short8*)(Bg + k0 + 40);
        }

        short8 af[4], bf[4];
        #pragma unroll
        for (int i = 0; i < 4; ++i)
            af[i] = *(const short8*)&As[(mq + i * 16 + lr) * LSTR + kq];
        #pragma unroll
        for (int j = 0; j < 4; ++j)
            bf[j] = *(const short8*)&Bs[(nq + j * 16 + lr) * LSTR + kq];
        #pragma unroll
        for (int i = 0; i < 4; ++i)
            #pragma unroll
            for (int j = 0; j < 4; ++j)
                acc[i][j] = __builtin_amdgcn_mfma_f32_16x16x32_bf16(af[i], bf[j], acc[i][j], 0, 0, 0);
    }

    const int rr = (L >> 4) * 4;
    #pragma unroll
    for (int i = 0; i < 4; ++i) {
        #pragma unroll
        for (int r = 0; r < 4; ++r) {
            int m = m0 + mq + i * 16 + rr + r;
            if (m < M) {
                #pragma unroll
                for (int j = 0; j < 4; ++j) {
                    int n = n0 + nq + j * 16 + lr;
                    C[(size_t)m * 256 + n] = acc[i][j][r] + bias[n];
                }
            }
        }
    }
}

// ---------------------------------------------------------------------------
// Sampler v7 = R8's sample5 (LDS (wt,idx) tables, 69 us proven) with phase 4
// rebuilt as an explicitly double-buffered pipeline: groups of 8 samples
// (2 lps); group g+1's 8 gathers are issued BEFORE group g's fmas consume
// their data -> >=8 loads in flight per wave (was ~4 with immediate use).
// Numerics bit-identical: same fma order per accumulator.
// ---------------------------------------------------------------------------
__global__ __launch_bounds__(256) void sample7(
    const unsigned short* __restrict__ value,  // bf16 [MTOT,256]
    const unsigned short* __restrict__ off,    // bf16 [MTOT,256]
    const unsigned short* __restrict__ attn,   // bf16 [MTOT,128]
    const float* __restrict__ refpts,          // [LEN_Q, LEVELS, 2]
    const int*   __restrict__ spatial,         // [LEVELS,2] (H,W)
    const int*   __restrict__ lsi,             // [LEVELS]
    unsigned short* __restrict__ samp)         // bf16 [MTOT,256]
{
    const int b = blockIdx.x;
    const int newb = (b & 7) * 831 + (b >> 3);   // XCD x gets a contiguous chunk
    if (newb * 4 >= MTOT) return;
    const int w = threadIdx.x >> 6;
    const int L = threadIdx.x & 63;
    const int row = newb * 4 + w;
    const int frame = row >= LEN_Q ? 1 : 0;
    const int q = row - frame * LEN_Q;

    __shared__ float attn_s[4][HEADS][16];
    __shared__ float w_s[4][HEADS][16][4];
    __shared__ int   idx_s[4][HEADS][16][4];

    // ---- phase 1: off kept in registers; attn -> LDS ----
    uint2v ov = *(const uint2v*)(off + (size_t)row * 256 + 4 * L);
    {
        unsigned av = *(const unsigned*)(attn + (size_t)row * 128 + 2 * L);
        int t0 = 2 * L;
        attn_s[w][t0 >> 4][t0 & 15] = bf2f((unsigned short)(av & 0xffffu));
        attn_s[w][(t0 + 1) >> 4][(t0 + 1) & 15] = bf2f((unsigned short)(av >> 16));
    }
    __syncthreads();

    // ---- phase 2: softmax per head ----
    if (L < 8) {
        float m = attn_s[w][L][0];
        #pragma unroll
        for (int i = 1; i < 16; ++i) m = fmaxf(m, attn_s[w][L][i]);
        float e[16]; float s = 0.f;
        #pragma unroll
        for (int i = 0; i < 16; ++i) { e[i] = __expf(attn_s[w][L][i] - m); s += e[i]; }
        float inv = 1.f / s;
        #pragma unroll
        for (int i = 0; i < 16; ++i) attn_s[w][L][i] = e[i] * inv;
    }
    __syncthreads();

    // ---- phase 3: loc (in-register) -> corner idx (byte) + weights ----
    #pragma unroll
    for (int i = 0; i < 2; ++i) {
        int e = 2 * L + i;
        int h = e >> 4;
        int lp = e & 15;
        int l = lp >> 2;
        int Hl = spatial[l * 2], Wl = spatial[l * 2 + 1];
        int start = lsi[l];
        unsigned sel = (i == 0) ? ov.x : ov.y;
        float ox = bf2f((unsigned short)(sel & 0xffffu));
        float oy = bf2f((unsigned short)(sel >> 16));
        float rx = refpts[((size_t)q * LEVELS + l) * 2];
        float ry = refpts[((size_t)q * LEVELS + l) * 2 + 1];
        float locx = rx + ox * __builtin_amdgcn_rcpf((float)Wl);
        float locy = ry + oy * __builtin_amdgcn_rcpf((float)Hl);
        float wt = attn_s[w][h][lp];
        float x = locx * (float)Wl - 0.5f;
        float y = locy * (float)Hl - 0.5f;
        float x0f = floorf(x), y0f = floorf(y);
        float lx = x - x0f, ly = y - y0f;
        int x0 = (int)x0f, y0 = (int)y0f;
        int x1 = x0 + 1, y1 = y0 + 1;
        int vx0 = (x0 >= 0) & (x0 < Wl);
        int vx1 = (x1 >= 0) & (x1 < Wl);
        int vy0 = (y0 >= 0) & (y0 < Hl);
        int vy1 = (y1 >= 0) & (y1 < Hl);
        int x0c = min(max(x0, 0), Wl - 1);
        int x1c = min(max(x1, 0), Wl - 1);
        int y0c = min(max(y0, 0), Hl - 1);
        int y1c = min(max(y1, 0), Hl - 1);
        idx_s[w][h][lp][0] = (start + y0c * Wl + x0c) * 512;
        idx_s[w][h][lp][1] = (start + y0c * Wl + x1c) * 512;
        idx_s[w][h][lp][2] = (start + y1c * Wl + x0c) * 512;
        idx_s[w][h][lp][3] = (start + y1c * Wl + x1c) * 512;
        w_s[w][h][lp][0] = (vy0 & vx0) ? wt * (1.f - lx) * (1.f - ly) : 0.f;
        w_s[w][h][lp][1] = (vy0 & vx1) ? wt * lx * (1.f - ly) : 0.f;
        w_s[w][h][lp][2] = (vy1 & vx0) ? wt * (1.f - lx) * ly : 0.f;
        w_s[w][h][lp][3] = (vy1 & vx1) ? wt * lx * ly : 0.f;
    }
    __syncthreads();

    // ---- phase 4: double-buffered gather pipeline (groups of 8 samples) ----
    const int h = L >> 3;
    const char* vbase = (const char*)value + (size_t)frame * LEN_Q * 512 + 8 * L;

    float  wbuf[2][8];
    uint2v vbuf[2][8];
    auto fetch = [&](int buf, int g) {
        #pragma unroll
        for (int j = 0; j < 8; ++j) {
            int lp = 2 * g + (j >> 2);
            int cr = j & 3;
            wbuf[buf][j] = w_s[w][h][lp][cr];
            int idx = idx_s[w][h][lp][cr];
            vbuf[buf][j] = *(const uint2v*)(vbase + (size_t)idx);
        }
    };

    float a0 = 0.f, a1 = 0.f, a2 = 0.f, a3 = 0.f;
    fetch(0, 0);
    #pragma unroll
    for (int g = 0; g < 8; ++g) {
        const int cur = g & 1;
        if (g < 7) fetch(cur ^ 1, g + 1);   // issue next group's loads first
        #pragma unroll
        for (int j = 0; j < 8; ++j) {
            float wc = wbuf[cur][j];
            uint2v v = vbuf[cur][j];
            a0 = fmaf(wc, __builtin_bit_cast(float, v.x << 16), a0);
            a1 = fmaf(wc, __builtin_bit_cast(float, v.x & 0xffff0000u), a1);
            a2 = fmaf(wc, __builtin_bit_cast(float, v.y << 16), a2);
            a3 = fmaf(wc, __builtin_bit_cast(float, v.y & 0xffff0000u), a3);
        }
    }
    ushort4v o;
    o.x = f2bf(a0); o.y = f2bf(a1); o.z = f2bf(a2); o.w = f2bf(a3);
    *(ushort4v*)(samp + (size_t)row * 256 + 4 * L) = o;
}

// ---------------------------------------------------------------------------
extern "C" void kernel_launch(void* const* d_in, const int* in_sizes, int n_in,
                              void* d_out, int out_size, void* d_ws, size_t ws_size,
                              hipStream_t stream)
{
    const float* query   = (const float*)d_in[0];
    const float* refpts  = (const float*)d_in[1];
    const float* inflat  = (const float*)d_in[2];
    const int*   spatial = (const int*)d_in[3];
    const int*   lsi     = (const int*)d_in[4];
    const float* Wv      = (const float*)d_in[5];
    const float* bv      = (const float*)d_in[6];
    const float* Woff    = (const float*)d_in[7];
    const float* boff    = (const float*)d_in[8];
    const float* Wattn   = (const float*)d_in[9];
    const float* battn   = (const float*)d_in[10];
    const float* Wout    = (const float*)d_in[11];
    const float* bout    = (const float*)d_in[12];

    unsigned short* ws = (unsigned short*)d_ws;
    const size_t MR = (size_t)MTOT * 256;
    unsigned short* v16    = ws;                        // MTOT*256
    unsigned short* off16  = v16 + MR;                  // MTOT*256
    unsigned short* at16   = off16 + MR;                // MTOT*128
    unsigned short* samp16 = at16 + (size_t)MTOT * 128; // MTOT*256
    unsigned short* wvT    = samp16 + MR;               // 256*256
    unsigned short* woaT   = wvT + 65536;               // 384*256
    unsigned short* woutT  = woaT + 98304;              // 256*256

    dim3 blk256(256);
    const int mBlocks = (MTOT + 127) / 128;             // 208

    hipLaunchKernelGGL(prep_weights, dim3(896), blk256, 0, stream,
                       Wv, Woff, Wattn, Wout, wvT, woaT, woutT);

    hipLaunchKernelGGL(gemm_fused, dim3(5, mBlocks), blk256, 0, stream,
                       inflat, query, wvT, woaT, bv, boff, battn,
                       v16, off16, at16, MTOT, 256);

    hipLaunchKernelGGL(sample7, dim3(6648), blk256, 0, stream,
                       v16, off16, at16, refpts, spatial, lsi, samp16);

    hipLaunchKernelGGL(gemm_out, dim3(2, mBlocks), blk256, 0, stream,
                       samp16, woutT, bout, (float*)d_out, MTOT, 256);
}